// Round 6
// baseline (130.519 us; speedup 1.0000x reference)
//
#include <hip/hip_runtime.h>

#define NE 24
#define NB 8192
#define FIN 15
#define H1 512
#define H2 512
#define H3 256
#define TS 64
#define SLOTS 130            // worst-case tiles per XCD (8192/64 + partials)
#define GRIDM (8 * SLOTS)    // 1040 blocks, idle ones exit immediately
#define PACKBLK 4803         // pack blocks; block PACKBLK does planning

// ---- ws layout ----
// int region (int32 offsets):
#define WS_OFF 0      // [25]  exclusive prefix of per-expert counts
#define WS_XN  32     // [8]   tiles per XCD
#define WS_XT  64     // [8*130] packed (e<<16)|tile
#define WS_ORD 4096   // [8192] sample ids grouped by expert
// bf16 region starts at byte 65536:
#define WB_BYTE 65536
#define OW1 0         // [24][4][512][8]
#define OW2 393216    // [24][64][512][8]
#define OW3 6684672   // [24][64][256][8]
#define OW4 9830400   // [24][256]

typedef __attribute__((ext_vector_type(8))) short short8v;
typedef __attribute__((ext_vector_type(4))) float f32x4;

__device__ __forceinline__ unsigned short f2bf(float x) {
  unsigned int u = __float_as_uint(x);
  unsigned int r = (u + 0x7fffu + ((u >> 16) & 1u)) >> 16;
  return (unsigned short)r;
}
__device__ __forceinline__ float bf2f(unsigned short h) {
  return __uint_as_float(((unsigned int)h) << 16);
}

// ---- fused pack + plan ----
__global__ __launch_bounds__(256) void k_pack(
    const float* __restrict__ W1, const float* __restrict__ W2,
    const float* __restrict__ W3, const float* __restrict__ W4,
    const int* __restrict__ midx, int* __restrict__ ws,
    unsigned short* __restrict__ wb) {
  const int t = threadIdx.x;
  if (blockIdx.x == PACKBLK) {
    __shared__ int hist[NE];
    __shared__ int off[NE + 1];
    __shared__ int cur[NE];
    __shared__ int tb[NE];
    __shared__ int xn[8];
    if (t < NE) hist[t] = 0;
    __syncthreads();
    int ev[32];
    #pragma unroll
    for (int r = 0; r < 32; ++r) {
      ev[r] = midx[r * 256 + t];
      atomicAdd(&hist[ev[r]], 1);
    }
    __syncthreads();
    if (t == 0) {
      int o = 0;
      #pragma unroll
      for (int i = 0; i < NE; ++i) { off[i] = o; cur[i] = o; o += hist[i]; }
      off[NE] = o;
    }
    if (t >= 32 && t < 40) {  // per-XCD tile-slot prefix, strided (no scratch)
      const int x = t - 32;
      int o = 0;
      for (int i = x; i < NE; i += 8) { tb[i] = o; o += (hist[i] + TS - 1) / TS; }
      xn[x] = o;
    }
    __syncthreads();
    if (t < NE + 1) ws[WS_OFF + t] = off[t];
    if (t >= 32 && t < 40) ws[WS_XN + t - 32] = xn[t - 32];
    for (int e = 0; e < NE; ++e) {
      const int nt = (hist[e] + TS - 1) / TS;
      for (int k = t; k < nt; k += 256)
        ws[WS_XT + (e & 7) * SLOTS + tb[e] + k] = (e << 16) | k;
    }
    #pragma unroll
    for (int r = 0; r < 32; ++r) {
      const int p = atomicAdd(&cur[ev[r]], 1);
      ws[WS_ORD + p] = r * 256 + t;
    }
    return;
  }
  int g = blockIdx.x * 256 + t;
  const float* src;
  unsigned short* dst;
  int Kb, N, KR;
  if (g < 49152) {
    src = W1; dst = wb + OW1; Kb = 4; N = 512; KR = 15;
  } else if (g < 49152 + 786432) {
    g -= 49152; src = W2; dst = wb + OW2; Kb = 64; N = 512; KR = 512;
  } else if (g < 49152 + 786432 + 393216) {
    g -= 49152 + 786432; src = W3; dst = wb + OW3; Kb = 64; N = 256; KR = 512;
  } else {
    g -= 49152 + 786432 + 393216; src = W4; dst = wb + OW4; Kb = 32; N = 1; KR = 256;
  }
  int e = g / (Kb * N);
  int r = g % (Kb * N);
  int kb = r / N;
  int n = r % N;
  short8v v;
  #pragma unroll
  for (int j = 0; j < 8; ++j) {
    int k = kb * 8 + j;
    float f = (k < KR) ? src[((size_t)e * KR + k) * N + n] : 0.f;
    v[j] = (short)f2bf(f);
  }
  *(short8v*)(dst + (size_t)g * 8) = v;
}

// MFMA layer, MT m-tiles (M = MT*16 = TS), NT n-tiles per wave, depth-3
// rotating B prefetch (ks loop fully unrolled -> all indices static).
// A in LDS [KS*4][TS][8], B global [KS*4][N][8], fp32 bias, relu,
// bf16 out to LDS [N/8][TS][8].
template <int NT, int KS, int MT>
__device__ __forceinline__ void layer_gemm(const unsigned short* __restrict__ aLDS,
                                           const unsigned short* __restrict__ bGlob,
                                           const float* __restrict__ bias,
                                           unsigned short* __restrict__ dLDS,
                                           int N, int ncol0, int lr, int lc) {
  f32x4 acc[MT][NT];
  #pragma unroll
  for (int mt = 0; mt < MT; ++mt)
    #pragma unroll
    for (int nt = 0; nt < NT; ++nt) acc[mt][nt] = (f32x4){0.f, 0.f, 0.f, 0.f};

  const unsigned short* bbase = bGlob + ((size_t)lc * N + ncol0 + lr) * 8;
  const size_t kstep = (size_t)4 * N * 8;  // one ks slice = 4 k-rows

  short8v bb[4][NT];
  #pragma unroll
  for (int p = 0; p < 3; ++p) {
    if (p < KS) {
      #pragma unroll
      for (int nt = 0; nt < NT; ++nt)
        bb[p][nt] = *(const short8v*)(bbase + p * kstep + nt * 128);
    }
  }
  #pragma unroll
  for (int ks = 0; ks < KS; ++ks) {
    if (ks + 3 < KS) {
      #pragma unroll
      for (int nt = 0; nt < NT; ++nt)
        bb[(ks + 3) & 3][nt] = *(const short8v*)(bbase + (ks + 3) * kstep + nt * 128);
    }
    const unsigned short* ap = aLDS + (((ks * 4 + lc) * TS) + lr) * 8;
    short8v a[MT];
    #pragma unroll
    for (int mt = 0; mt < MT; ++mt) a[mt] = *(const short8v*)(ap + mt * 128);
    #pragma unroll
    for (int nt = 0; nt < NT; ++nt)
      #pragma unroll
      for (int mt = 0; mt < MT; ++mt)
        acc[mt][nt] = __builtin_amdgcn_mfma_f32_16x16x32_bf16(a[mt], bb[ks & 3][nt], acc[mt][nt], 0, 0, 0);
  }
  #pragma unroll
  for (int nt = 0; nt < NT; ++nt) {
    const int col = ncol0 + nt * 16 + lr;
    const float bv = bias[col];
    #pragma unroll
    for (int mt = 0; mt < MT; ++mt) {
      #pragma unroll
      for (int j = 0; j < 4; ++j) {
        const int row = mt * 16 + lc * 4 + j;
        const float v = fmaxf(acc[mt][nt][j] + bv, 0.f);
        dLDS[(((col >> 3) * TS) + row) * 8 + (col & 7)] = f2bf(v);
      }
    }
  }
}

__global__ __launch_bounds__(512, 2) void k_mlp(
    const float* __restrict__ features,
    const float* __restrict__ b1, const float* __restrict__ b2,
    const float* __restrict__ b3, const float* __restrict__ b4,
    const int* __restrict__ ws, const unsigned short* __restrict__ wb,
    float* __restrict__ out) {
  __shared__ int sidx[TS];
  __shared__ __align__(16) unsigned short fA[4][TS][8];     // 4 KB
  __shared__ __align__(16) unsigned short actA[64][TS][8];  // 64 KB
  __shared__ __align__(16) unsigned short actB[64][TS][8];  // 64 KB

  const int t = threadIdx.x;
  const int wv = t >> 6;   // 0..7
  const int ln = t & 63;
  const int lr = ln & 15;
  const int lc = ln >> 4;

  const int bid = blockIdx.x;
  const int xcd = bid & 7;
  const int slot = bid >> 3;
  if (slot >= ws[WS_XN + xcd]) return;  // block-uniform
  const int packed = ws[WS_XT + xcd * SLOTS + slot];
  const int e = packed >> 16;
  const int tt = packed & 0xffff;
  const int start = ws[WS_OFF + e] + tt * TS;
  const int cnt = min(TS, ws[WS_OFF + e + 1] - start);

  if (t < TS) sidx[t] = (t < cnt) ? ws[WS_ORD + start + t] : ws[WS_ORD + start];
  __syncthreads();

  if (t < 256) {  // stage features as A-fragments (K padded to 32)
    int m = t >> 2, cb = t & 3;
    #pragma unroll
    for (int j = 0; j < 8; ++j) {
      int k = cb * 8 + j;
      fA[cb][m][j] = (k < FIN) ? f2bf(features[(size_t)sidx[m] * FIN + k]) : 0;
    }
  }
  __syncthreads();

  const unsigned short* w1p = wb + OW1 + (size_t)e * 4 * 512 * 8;
  const unsigned short* w2p = wb + OW2 + (size_t)e * 64 * 512 * 8;
  const unsigned short* w3p = wb + OW3 + (size_t)e * 64 * 256 * 8;
  const unsigned short* w4p = wb + OW4 + (size_t)e * 256;

  layer_gemm<4, 1, 4>(&fA[0][0][0], w1p, b1 + e * H1, &actA[0][0][0], 512, wv * 64, lr, lc);
  __syncthreads();
  layer_gemm<4, 16, 4>(&actA[0][0][0], w2p, b2 + e * H2, &actB[0][0][0], 512, wv * 64, lr, lc);
  __syncthreads();
  layer_gemm<2, 16, 4>(&actB[0][0][0], w3p, b3 + e * H3, &actA[0][0][0], 256, wv * 32, lr, lc);
  __syncthreads();

  // layer 4: out[m] = h3[m][:] . W4 + b4, 8 threads per sample (512 thr = 64 samples)
  {
    int m = t >> 3, c = t & 7;
    float p = 0.f;
    #pragma unroll
    for (int kk = 0; kk < 32; ++kk)
      p += bf2f(actA[0][0][(kk * TS + m) * 8 + c]) * bf2f(w4p[kk * 8 + c]);
    p += __shfl_xor(p, 1);
    p += __shfl_xor(p, 2);
    p += __shfl_xor(p, 4);
    if (c == 0 && m < cnt) out[sidx[m]] = p + b4[e];
  }
}

extern "C" void kernel_launch(void* const* d_in, const int* in_sizes, int n_in,
                              void* d_out, int out_size, void* d_ws, size_t ws_size,
                              hipStream_t stream) {
  const float* features = (const float*)d_in[0];
  const int* midx = (const int*)d_in[1];
  const float* W1 = (const float*)d_in[2];
  const float* b1 = (const float*)d_in[3];
  const float* W2 = (const float*)d_in[4];
  const float* b2 = (const float*)d_in[5];
  const float* W3 = (const float*)d_in[6];
  const float* b3 = (const float*)d_in[7];
  const float* W4 = (const float*)d_in[8];
  const float* b4 = (const float*)d_in[9];
  int* ws = (int*)d_ws;
  unsigned short* wb = (unsigned short*)((char*)d_ws + WB_BYTE);
  float* out = (float*)d_out;

  k_pack<<<PACKBLK + 1, 256, 0, stream>>>(W1, W2, W3, W4, midx, ws, wb);
  k_mlp<<<GRIDM, 512, 0, stream>>>(features, b1, b2, b3, b4, ws, wb, out);
}